// Round 6
// baseline (359.851 us; speedup 1.0000x reference)
//
#include <hip/hip_runtime.h>

typedef short s16x8 __attribute__((ext_vector_type(8)));
typedef unsigned short u16x8 __attribute__((ext_vector_type(8)));
typedef float f32x4 __attribute__((ext_vector_type(4)));
typedef unsigned short ushort;

// ---------------- problem constants ----------------
#define NTOK 1024
#define DHID 512

// head: W0 (20000) + cluster_weight (3) = 20003 rows, K=512
#define VH   20003
#define KH   512
#define NCH_H 160
#define TPC_H 8       // 160 chunks * 8 tiles * 16 = 20480 padded rows
#define VH_PAD 20480

// tail1: 20000 rows, K=128
#define V1   20000
#define K1   128
#define NCH_1 160
#define TPC_1 8       // 20480
#define V1_PAD 20480

// tail2: 160000 rows, K=32
#define V2   160000
#define K2   32
#define NCH_2 256
#define TPC_2 40      // 256*40*16 = 163840
#define V2_PAD 163840

// tail3: 67735 rows, K=8 padded to 32
#define V3   67735
#define K3   32
#define NCH_3 134
#define TPC_3 32      // 134*32*16 = 68608
#define V3_PAD 68608

#define PAD_BIAS (-1e30f)

// ---------------- ws layout (bytes) ----------------
#define OFF_HW   0UL
#define OFF_W1   (OFF_HW  + (unsigned long)VH_PAD*KH*2)
#define OFF_W2   (OFF_W1  + (unsigned long)V1_PAD*K1*2)
#define OFF_W3   (OFF_W2  + (unsigned long)V2_PAD*K2*2)
#define OFF_HID  (OFF_W3  + (unsigned long)V3_PAD*K3*2)
#define OFF_PT0  (OFF_HID + (unsigned long)NTOK*DHID*2)
#define OFF_PT1  (OFF_PT0 + (unsigned long)512*DHID*2)
#define OFF_PT2  (OFF_PT1 + (unsigned long)128*DHID*2)
#define OFF_PT3  (OFF_PT2 + (unsigned long)32*DHID*2)
#define OFF_H0   (OFF_PT3 + (unsigned long)32*DHID*2)
#define OFF_H1   (OFF_H0  + (unsigned long)NTOK*512*2)
#define OFF_H2   (OFF_H1  + (unsigned long)NTOK*128*2)
#define OFF_H3   (OFF_H2  + (unsigned long)NTOK*32*2)
#define OFF_HB   (OFF_H3  + (unsigned long)NTOK*32*2)
#define OFF_B1   (OFF_HB  + (unsigned long)VH_PAD*4)
#define OFF_B2   (OFF_B1  + (unsigned long)V1_PAD*4)
#define OFF_B3   (OFF_B2  + (unsigned long)V2_PAD*4)
#define OFF_SH   (OFF_B3  + (unsigned long)V3_PAD*4)
#define OFF_S1   (OFF_SH  + (unsigned long)NTOK*NCH_H*4)
#define OFF_S2   (OFF_S1  + (unsigned long)NTOK*NCH_1*4)
#define OFF_S3   (OFF_S2  + (unsigned long)NTOK*NCH_2*4)

// ---------------- helpers ----------------
__device__ __forceinline__ ushort f2bf(float f) {
    union { float f; unsigned u; } x; x.f = f;
    unsigned r = x.u + 0x7fffu + ((x.u >> 16) & 1u);
    return (ushort)(r >> 16);
}
__device__ __forceinline__ float bf2f(ushort h) {
    union { unsigned u; float f; } x; x.u = ((unsigned)h) << 16;
    return x.f;
}
__device__ __forceinline__ f32x4 mfma_bf16(s16x8 a, s16x8 b, f32x4 c) {
    return __builtin_amdgcn_mfma_f32_16x16x32_bf16(a, b, c, 0, 0, 0);
}
__device__ __forceinline__ void ld8(const float* p, float* v) {
    float4 a = *(const float4*)p, b = *(const float4*)(p + 4);
    v[0]=a.x; v[1]=a.y; v[2]=a.z; v[3]=a.w; v[4]=b.x; v[5]=b.y; v[6]=b.z; v[7]=b.w;
}

// ---------------- prep: wave-per-512-element-block swizzle ----------------
#define WB_HW  20480L
#define WB_W1  5120L
#define WB_W2  10240L
#define WB_W3  4288L
#define WB_HID 1024L
#define WB_PT0 512L
#define WB_PT1 128L
#define WB_PT2 32L
#define WB_PT3 32L
#define WB_TOTAL (WB_HW+WB_W1+WB_W2+WB_W3+WB_HID+WB_PT0+WB_PT1+WB_PT2+WB_PT3)

__global__ __launch_bounds__(256) void prep_wswz(
    const float* __restrict__ hidden,
    const float* __restrict__ W0, const float* __restrict__ cw,
    const float* __restrict__ W1, const float* __restrict__ W2, const float* __restrict__ W3,
    const float* __restrict__ p0, const float* __restrict__ p1,
    const float* __restrict__ p2, const float* __restrict__ p3,
    ushort* __restrict__ hw, ushort* __restrict__ ow1,
    ushort* __restrict__ ow2, ushort* __restrict__ ow3,
    ushort* __restrict__ hid,
    ushort* __restrict__ pT0, ushort* __restrict__ pT1,
    ushort* __restrict__ pT2, ushort* __restrict__ pT3)
{
    int lane = threadIdx.x & 63;
    int r = lane & 15, quad = lane >> 4;
    long wb0 = (long)blockIdx.x * 4 + (threadIdx.x >> 6);
    long nw = (long)gridDim.x * 4;
    for (long wb = wb0; wb < WB_TOTAL; wb += nw) {
        long b = wb;
        float vals[8];
        #pragma unroll
        for (int j = 0; j < 8; ++j) vals[j] = 0.f;
        ushort* dst;
        if (b < WB_HW) {
            long tile = b >> 4, ks = b & 15;
            long v = tile * 16 + r, k = ks * 32 + quad * 8;
            if (v < 20000)      ld8(W0 + v * 512 + k, vals);
            else if (v < VH)    ld8(cw + (v - 20000) * 512 + k, vals);
            dst = hw + b * 512 + (long)lane * 8;
        } else if ((b -= WB_HW) < WB_W1) {
            long tile = b >> 2, ks = b & 3;
            long v = tile * 16 + r, k = ks * 32 + quad * 8;
            if (v < V1) ld8(W1 + v * 128 + k, vals);
            dst = ow1 + b * 512 + (long)lane * 8;
        } else if ((b -= WB_W1) < WB_W2) {
            long v = b * 16 + r;
            if (v < V2) ld8(W2 + v * 32 + quad * 8, vals);
            dst = ow2 + b * 512 + (long)lane * 8;
        } else if ((b -= WB_W2) < WB_W3) {
            long v = b * 16 + r;
            if (v < V3 && quad == 0) ld8(W3 + v * 8, vals);
            dst = ow3 + b * 512 + (long)lane * 8;
        } else if ((b -= WB_W3) < WB_HID) {
            long tile = b >> 4, ks = b & 15;
            long v = tile * 16 + r, k = ks * 32 + quad * 8;
            ld8(hidden + v * 512 + k, vals);
            dst = hid + b * 512 + (long)lane * 8;
        } else if ((b -= WB_HID) < WB_PT0) {
            long tile = b >> 4, ks = b & 15;
            long c = tile * 16 + r, k = ks * 32 + quad * 8;
            #pragma unroll
            for (int j = 0; j < 8; ++j) vals[j] = p0[(k + j) * 512 + c];
            dst = pT0 + b * 512 + (long)lane * 8;
        } else if ((b -= WB_PT0) < WB_PT1) {
            long tile = b >> 4, ks = b & 15;
            long c = tile * 16 + r, k = ks * 32 + quad * 8;
            #pragma unroll
            for (int j = 0; j < 8; ++j) vals[j] = p1[(k + j) * 128 + c];
            dst = pT1 + b * 512 + (long)lane * 8;
        } else if ((b -= WB_PT1) < WB_PT2) {
            long tile = b >> 4, ks = b & 15;
            long c = tile * 16 + r, k = ks * 32 + quad * 8;
            #pragma unroll
            for (int j = 0; j < 8; ++j) vals[j] = p2[(k + j) * 32 + c];
            dst = pT2 + b * 512 + (long)lane * 8;
        } else {
            b -= WB_PT2;
            long tile = b >> 4, ks = b & 15;
            long c = tile * 16 + r, k = ks * 32 + quad * 8;
            if (c < 8) {
                #pragma unroll
                for (int j = 0; j < 8; ++j) vals[j] = p3[(k + j) * 8 + c];
            }
            dst = pT3 + b * 512 + (long)lane * 8;
        }
        u16x8 o;
        #pragma unroll
        for (int j = 0; j < 8; ++j) o[j] = f2bf(vals[j]);
        *(u16x8*)dst = o;
    }
}

// ---------------- prep: padded biases ----------------
#define E_HB  ((long)VH_PAD)
#define E_B1  ((long)V1_PAD)
#define E_B2  ((long)V2_PAD)
#define E_B3  ((long)V3_PAD)
#define E_BIAS (E_HB+E_B1+E_B2+E_B3)

__global__ __launch_bounds__(256) void prep_bias(
    const float* __restrict__ b0, const float* __restrict__ b1,
    const float* __restrict__ b2, const float* __restrict__ b3,
    const float* __restrict__ cb,
    float* __restrict__ hbp, float* __restrict__ ob1,
    float* __restrict__ ob2, float* __restrict__ ob3)
{
    long stride = (long)gridDim.x * blockDim.x;
    for (long i = (long)blockIdx.x * blockDim.x + threadIdx.x; i < E_BIAS; i += stride) {
        long j = i;
        if (j < E_HB) {
            hbp[j] = (j < 20000) ? b0[j] : (j < VH) ? cb[j - 20000] : PAD_BIAS;
        } else if ((j -= E_HB) < E_B1) {
            ob1[j] = (j < V1) ? b1[j] : PAD_BIAS;
        } else if ((j -= E_B1) < E_B2) {
            ob2[j] = (j < V2) ? b2[j] : PAD_BIAS;
        } else { j -= E_B2;
            ob3[j] = (j < V3) ? b3[j] : PAD_BIAS;
        }
    }
}

// ---------------- gemm_h ----------------
__global__ __launch_bounds__(256) void gemm_h(
    const ushort* __restrict__ A, const ushort* __restrict__ Bt,
    ushort* __restrict__ Hout, int dpad)
{
    int wave = threadIdx.x >> 6, lane = threadIdx.x & 63;
    int quad = lane >> 4, colid = lane & 15;
    int m_tile = blockIdx.x * 4 + wave;
    int c_tile = blockIdx.y;
    const ushort* Ab = A + ((long)m_tile * 16) * 512 + lane * 8;
    const ushort* Bb = Bt + ((long)c_tile * 16) * 512 + lane * 8;
    f32x4 acc = {0.f, 0.f, 0.f, 0.f};
    #pragma unroll
    for (int ks = 0; ks < 16; ++ks) {
        s16x8 a = *(const s16x8*)(Ab + ks * 512);
        s16x8 b = *(const s16x8*)(Bb + ks * 512);
        acc = mfma_bf16(a, b, acc);
    }
    int KBo = dpad >> 5;
    int col = c_tile * 16 + colid;
    int ks_o = col >> 5, q_o = (col >> 3) & 3, j_o = col & 7;
    #pragma unroll
    for (int r = 0; r < 4; ++r) {
        int rm = quad * 4 + r;
        Hout[((long)m_tile * KBo + ks_o) * 512 + (q_o * 16 + rm) * 8 + j_o] = f2bf(acc[r]);
    }
}

// ---------------- fused GEMM + exp-sum, K>=128 ----------------
// 256-thread blocks, 4 waves; each wave: M m-tiles x U vocab tiles in registers.
// launch_bounds(256,2): 256-VGPR cap -> the ~130-reg tile CANNOT spill.
// (r5 post-mortem: (256,3) capped at ~148 and spilled acc -> 156 MB scratch writes.)
template<int K, int U, int M>
__global__ __launch_bounds__(256, 2) void fused_lse_big(
    const ushort* __restrict__ A, const ushort* __restrict__ W,
    const float* __restrict__ bias, float* __restrict__ part_s,
    int tpc, int n_chunks)
{
    constexpr int KB = K / 32;
    int wave = threadIdx.x >> 6, lane = threadIdx.x & 63;
    int quad = lane >> 4, colid = lane & 15;
    int mt0 = (blockIdx.x * 4 + wave) * M;
    int chunk = blockIdx.y;
    int t0 = chunk * tpc;
    const ushort* Ab = A + (long)mt0 * KB * 512 + lane * 8;

    float s_acc[M][4];
    #pragma unroll
    for (int t = 0; t < M; ++t)
        #pragma unroll
        for (int r = 0; r < 4; ++r) s_acc[t][r] = 0.f;

    for (int vt = 0; vt < tpc; vt += U) {
        const ushort* Wb = W + ((long)(t0 + vt) * KB) * 512 + lane * 8;
        f32x4 acc[M][U];
        #pragma unroll
        for (int t = 0; t < M; ++t)
            #pragma unroll
            for (int u = 0; u < U; ++u) acc[t][u] = (f32x4){0.f, 0.f, 0.f, 0.f};
        #pragma unroll
        for (int ks = 0; ks < KB; ++ks) {
            s16x8 b[U];
            #pragma unroll
            for (int u = 0; u < U; ++u)
                b[u] = *(const s16x8*)(Wb + ((long)u * KB + ks) * 512);
            s16x8 a[M];
            #pragma unroll
            for (int t = 0; t < M; ++t)
                a[t] = *(const s16x8*)(Ab + ((long)t * KB + ks) * 512);
            #pragma unroll
            for (int t = 0; t < M; ++t)
                #pragma unroll
                for (int u = 0; u < U; ++u)
                    acc[t][u] = mfma_bf16(a[t], b[u], acc[t][u]);
        }
        #pragma unroll
        for (int u = 0; u < U; ++u) {
            float bval = bias[(t0 + vt + u) * 16 + colid];
            #pragma unroll
            for (int t = 0; t < M; ++t)
                #pragma unroll
                for (int r = 0; r < 4; ++r)
                    s_acc[t][r] += __expf(acc[t][u][r] + bval);
        }
    }
    #pragma unroll
    for (int t = 0; t < M; ++t)
        #pragma unroll
        for (int r = 0; r < 4; ++r) {
            float v = s_acc[t][r];
            v += __shfl_xor(v, 1);
            v += __shfl_xor(v, 2);
            v += __shfl_xor(v, 4);
            v += __shfl_xor(v, 8);
            if (colid == 0) {
                int m = (mt0 + t) * 16 + quad * 4 + r;
                part_s[(long)m * n_chunks + chunk] = v;
            }
        }
}

// ---------------- fused GEMM + exp-sum, K==32 (A fully hoisted) ----------------
// acc produced and consumed within each vt body -> short live ranges, no spill.
template<int U, int M>
__global__ __launch_bounds__(256, 4) void fused_lse_small(
    const ushort* __restrict__ A, const ushort* __restrict__ W,
    const float* __restrict__ bias, float* __restrict__ part_s,
    int tpc, int n_chunks)
{
    int wave = threadIdx.x >> 6, lane = threadIdx.x & 63;
    int quad = lane >> 4, colid = lane & 15;
    int mt0 = (blockIdx.x * 4 + wave) * M;
    int chunk = blockIdx.y;
    int t0 = chunk * tpc;
    const ushort* Ab = A + (long)mt0 * 512 + lane * 8;

    s16x8 af[M];
    #pragma unroll
    for (int t = 0; t < M; ++t)
        af[t] = *(const s16x8*)(Ab + (long)t * 512);

    float s_acc[M][4];
    #pragma unroll
    for (int t = 0; t < M; ++t)
        #pragma unroll
        for (int r = 0; r < 4; ++r) s_acc[t][r] = 0.f;

    for (int vt = 0; vt < tpc; vt += U) {
        const ushort* Wb = W + (long)(t0 + vt) * 512 + lane * 8;
        s16x8 b[U];
        #pragma unroll
        for (int u = 0; u < U; ++u)
            b[u] = *(const s16x8*)(Wb + (long)u * 512);
        #pragma unroll
        for (int u = 0; u < U; ++u) {
            float bval = bias[(t0 + vt + u) * 16 + colid];
            #pragma unroll
            for (int t = 0; t < M; ++t) {
                f32x4 acc = {0.f, 0.f, 0.f, 0.f};
                acc = mfma_bf16(af[t], b[u], acc);
                #pragma unroll
                for (int r = 0; r < 4; ++r)
                    s_acc[t][r] += __expf(acc[r] + bval);
            }
        }
    }
    #pragma unroll
    for (int t = 0; t < M; ++t)
        #pragma unroll
        for (int r = 0; r < 4; ++r) {
            float v = s_acc[t][r];
            v += __shfl_xor(v, 1);
            v += __shfl_xor(v, 2);
            v += __shfl_xor(v, 4);
            v += __shfl_xor(v, 8);
            if (colid == 0) {
                int m = (mt0 + t) * 16 + quad * 4 + r;
                part_s[(long)m * n_chunks + chunk] = v;
            }
        }
}

// ---------------- finalize ----------------
__device__ __forceinline__ float swz_dot(const ushort* __restrict__ H, int m,
                                         const ushort* __restrict__ Wm, long vrow,
                                         int K, int lane)
{
    float d = 0.f;
    if (lane * 8 < K) {
        int ks = lane >> 2, q = lane & 3;
        int KB = K >> 5;
        const ushort* hp = H + ((long)(m >> 4) * KB + ks) * 512 + (q * 16 + (m & 15)) * 8;
        const ushort* wp = Wm + ((vrow >> 4) * KB + ks) * 512 + (q * 16 + (int)(vrow & 15)) * 8;
        #pragma unroll
        for (int j = 0; j < 8; ++j) d += bf2f(hp[j]) * bf2f(wp[j]);
    }
    d += __shfl_xor(d, 1);  d += __shfl_xor(d, 2);  d += __shfl_xor(d, 4);
    d += __shfl_xor(d, 8);  d += __shfl_xor(d, 16); d += __shfl_xor(d, 32);
    return d;
}

__global__ __launch_bounds__(256) void finalize_kernel(
    const int* __restrict__ target,
    const ushort* __restrict__ H0, const ushort* __restrict__ hw,
    const float* __restrict__ hbp, const float* __restrict__ sH,
    const ushort* __restrict__ H1, const ushort* __restrict__ w1,
    const float* __restrict__ b1p, const float* __restrict__ s1,
    const ushort* __restrict__ H2, const ushort* __restrict__ w2,
    const float* __restrict__ b2p, const float* __restrict__ s2,
    const ushort* __restrict__ H3, const ushort* __restrict__ w3,
    const float* __restrict__ b3p, const float* __restrict__ s3,
    float* __restrict__ out)
{
    int wave = threadIdx.x >> 6, lane = threadIdx.x & 63;
    int m = blockIdx.x * 4 + wave;
    int t = target[m];
    int cid = (t >= 20000) + (t >= 40000) + (t >= 200000);

    float s = 0.f;
    for (int i = lane; i < NCH_H; i += 64) s += sH[(long)m * NCH_H + i];
    s += __shfl_xor(s, 1);  s += __shfl_xor(s, 2);  s += __shfl_xor(s, 4);
    s += __shfl_xor(s, 8);  s += __shfl_xor(s, 16); s += __shfl_xor(s, 32);
    float lse_h = __logf(s);

    int hc = (cid == 0) ? t : (20003 - cid);
    float d = swz_dot(H0, m, hw, hc, 512, lane);
    float nll = lse_h - (d + hbp[hc]);

    if (cid > 0) {
        const ushort *Hi, *Wi; const float *bi, *si; int K, nc, l;
        if (cid == 1)      { Hi = H1; Wi = w1; bi = b1p; si = s1; K = 128; nc = NCH_1; l = 20000; }
        else if (cid == 2) { Hi = H2; Wi = w2; bi = b2p; si = s2; K = 32;  nc = NCH_2; l = 40000; }
        else               { Hi = H3; Wi = w3; bi = b3p; si = s3; K = 32;  nc = NCH_3; l = 200000; }
        int rel = t - l;
        float ts = 0.f;
        for (int i = lane; i < nc; i += 64) ts += si[(long)m * nc + i];
        ts += __shfl_xor(ts, 1);  ts += __shfl_xor(ts, 2);  ts += __shfl_xor(ts, 4);
        ts += __shfl_xor(ts, 8);  ts += __shfl_xor(ts, 16); ts += __shfl_xor(ts, 32);
        float lse_t = __logf(ts);
        float dt = swz_dot(Hi, m, Wi, rel, K, lane);
        nll += lse_t - (dt + bi[rel]);
    }
    if (lane == 0) out[m] = nll;
}

// ---------------- host ----------------
extern "C" void kernel_launch(void* const* d_in, const int* in_sizes, int n_in,
                              void* d_out, int out_size, void* d_ws, size_t ws_size,
                              hipStream_t stream) {
    const float* hidden = (const float*)d_in[0];
    const int*   target = (const int*)d_in[1];
    const float* W0 = (const float*)d_in[2];
    const float* b0 = (const float*)d_in[3];
    const float* p0 = (const float*)d_in[4];
    const float* W1 = (const float*)d_in[5];
    const float* b1 = (const float*)d_in[6];
    const float* p1 = (const float*)d_in[7];
    const float* W2 = (const float*)d_in[8];
    const float* b2 = (const float*)d_in[9];
    const float* p2 = (const float*)d_in[10];
    const float* W3 = (const float*)d_in[11];
    const float* b3 = (const float*)d_in[12];
    const float* p3 = (const float*)d_in[13];
    const float* cw = (const float*)d_in[14];
    const float* cb = (const float*)d_in[15];

    char* ws = (char*)d_ws;
    ushort* hw  = (ushort*)(ws + OFF_HW);
    ushort* ow1 = (ushort*)(ws + OFF_W1);
    ushort* ow2 = (ushort*)(ws + OFF_W2);
    ushort* ow3 = (ushort*)(ws + OFF_W3);
    ushort* hid = (ushort*)(ws + OFF_HID);
    ushort* pT0 = (ushort*)(ws + OFF_PT0);
    ushort* pT1 = (ushort*)(ws + OFF_PT1);
    ushort* pT2 = (ushort*)(ws + OFF_PT2);
    ushort* pT3 = (ushort*)(ws + OFF_PT3);
    ushort* H0  = (ushort*)(ws + OFF_H0);
    ushort* H1  = (ushort*)(ws + OFF_H1);
    ushort* H2  = (ushort*)(ws + OFF_H2);
    ushort* H3  = (ushort*)(ws + OFF_H3);
    float* hbp = (float*)(ws + OFF_HB);
    float* b1p = (float*)(ws + OFF_B1);
    float* b2p = (float*)(ws + OFF_B2);
    float* b3p = (float*)(ws + OFF_B3);
    float* sH  = (float*)(ws + OFF_SH);
    float* s1  = (float*)(ws + OFF_S1);
    float* s2  = (float*)(ws + OFF_S2);
    float* s3  = (float*)(ws + OFF_S3);

    prep_wswz<<<10464, 256, 0, stream>>>(hidden, W0, cw, W1, W2, W3,
                                         p0, p1, p2, p3,
                                         hw, ow1, ow2, ow3, hid, pT0, pT1, pT2, pT3);
    prep_bias<<<1072, 256, 0, stream>>>(b0, b1, b2, b3, cb, hbp, b1p, b2p, b3p);

    gemm_h<<<dim3(NTOK / 64, 512 / 16), 256, 0, stream>>>(hid, pT0, H0, 512);
    gemm_h<<<dim3(NTOK / 64, 128 / 16), 256, 0, stream>>>(hid, pT1, H1, 128);
    gemm_h<<<dim3(NTOK / 64, 32 / 16),  256, 0, stream>>>(hid, pT2, H2, 32);
    gemm_h<<<dim3(NTOK / 64, 32 / 16),  256, 0, stream>>>(hid, pT3, H3, 32);

    // x=4 blocks cover all 1024 tokens (4 waves * M=4 m-tiles * 16 tokens each)
    fused_lse_big<KH, 4, 4><<<dim3(4, NCH_H), 256, 0, stream>>>(H0, hw,  hbp, sH, TPC_H, NCH_H);
    fused_lse_big<K1, 4, 4><<<dim3(4, NCH_1), 256, 0, stream>>>(H1, ow1, b1p, s1, TPC_1, NCH_1);
    fused_lse_small<4, 4><<<dim3(4, NCH_2), 256, 0, stream>>>(H2, ow2, b2p, s2, TPC_2, NCH_2);
    fused_lse_small<4, 4><<<dim3(4, NCH_3), 256, 0, stream>>>(H3, ow3, b3p, s3, TPC_3, NCH_3);

    finalize_kernel<<<NTOK / 4, 256, 0, stream>>>(target,
        H0, hw, hbp, sH, H1, ow1, b1p, s1, H2, ow2, b2p, s2, H3, ow3, b3p, s3,
        (float*)d_out);
}

// Round 7
// 292.959 us; speedup vs baseline: 1.2283x; 1.2283x over previous
//
#include <hip/hip_runtime.h>

typedef short s16x8 __attribute__((ext_vector_type(8)));
typedef unsigned short u16x8 __attribute__((ext_vector_type(8)));
typedef float f32x4 __attribute__((ext_vector_type(4)));
typedef unsigned short ushort;

// ---------------- problem constants ----------------
#define NTOK 1024
#define DHID 512

// head: W0 (20000) + cluster_weight (3) = 20003 rows, K=512
#define VH   20003
#define KH   512
#define NCH_H 160
#define TPC_H 8       // 160 chunks * 8 tiles * 16 = 20480 padded rows
#define VH_PAD 20480

// tail1: 20000 rows, K=128
#define V1   20000
#define K1   128
#define NCH_1 160
#define TPC_1 8       // 20480
#define V1_PAD 20480

// tail2: 160000 rows, K=32
#define V2   160000
#define K2   32
#define NCH_2 256
#define TPC_2 40      // 256*40*16 = 163840
#define V2_PAD 163840

// tail3: 67735 rows, K=8 padded to 32
#define V3   67735
#define K3   32
#define NCH_3 134
#define TPC_3 32      // 134*32*16 = 68608
#define V3_PAD 68608

#define PAD_BIAS (-1e30f)

// ---------------- ws layout (bytes) ----------------
#define OFF_HW   0UL
#define OFF_W1   (OFF_HW  + (unsigned long)VH_PAD*KH*2)
#define OFF_W2   (OFF_W1  + (unsigned long)V1_PAD*K1*2)
#define OFF_W3   (OFF_W2  + (unsigned long)V2_PAD*K2*2)
#define OFF_HID  (OFF_W3  + (unsigned long)V3_PAD*K3*2)
#define OFF_PT0  (OFF_HID + (unsigned long)NTOK*DHID*2)
#define OFF_PT1  (OFF_PT0 + (unsigned long)512*DHID*2)
#define OFF_PT2  (OFF_PT1 + (unsigned long)128*DHID*2)
#define OFF_PT3  (OFF_PT2 + (unsigned long)32*DHID*2)
#define OFF_H0   (OFF_PT3 + (unsigned long)32*DHID*2)
#define OFF_H1   (OFF_H0  + (unsigned long)NTOK*512*2)
#define OFF_H2   (OFF_H1  + (unsigned long)NTOK*128*2)
#define OFF_H3   (OFF_H2  + (unsigned long)NTOK*32*2)
#define OFF_HB   (OFF_H3  + (unsigned long)NTOK*32*2)
#define OFF_B1   (OFF_HB  + (unsigned long)VH_PAD*4)
#define OFF_B2   (OFF_B1  + (unsigned long)V1_PAD*4)
#define OFF_B3   (OFF_B2  + (unsigned long)V2_PAD*4)
#define OFF_SH   (OFF_B3  + (unsigned long)V3_PAD*4)
#define OFF_S1   (OFF_SH  + (unsigned long)NTOK*NCH_H*4)
#define OFF_S2   (OFF_S1  + (unsigned long)NTOK*NCH_1*4)
#define OFF_S3   (OFF_S2  + (unsigned long)NTOK*NCH_2*4)

// ---------------- helpers ----------------
__device__ __forceinline__ ushort f2bf(float f) {
    union { float f; unsigned u; } x; x.f = f;
    unsigned r = x.u + 0x7fffu + ((x.u >> 16) & 1u);
    return (ushort)(r >> 16);
}
__device__ __forceinline__ float bf2f(ushort h) {
    union { unsigned u; float f; } x; x.u = ((unsigned)h) << 16;
    return x.f;
}
__device__ __forceinline__ f32x4 mfma_bf16(s16x8 a, s16x8 b, f32x4 c) {
    return __builtin_amdgcn_mfma_f32_16x16x32_bf16(a, b, c, 0, 0, 0);
}
__device__ __forceinline__ void ld8(const float* p, float* v) {
    float4 a = *(const float4*)p, b = *(const float4*)(p + 4);
    v[0]=a.x; v[1]=a.y; v[2]=a.z; v[3]=a.w; v[4]=b.x; v[5]=b.y; v[6]=b.z; v[7]=b.w;
}

// ---------------- prep: wave-per-512-element-block swizzle ----------------
#define WB_HW  20480L
#define WB_W1  5120L
#define WB_W2  10240L
#define WB_W3  4288L
#define WB_HID 1024L
#define WB_PT0 512L
#define WB_PT1 128L
#define WB_PT2 32L
#define WB_PT3 32L
#define WB_TOTAL (WB_HW+WB_W1+WB_W2+WB_W3+WB_HID+WB_PT0+WB_PT1+WB_PT2+WB_PT3)

__global__ __launch_bounds__(256) void prep_wswz(
    const float* __restrict__ hidden,
    const float* __restrict__ W0, const float* __restrict__ cw,
    const float* __restrict__ W1, const float* __restrict__ W2, const float* __restrict__ W3,
    const float* __restrict__ p0, const float* __restrict__ p1,
    const float* __restrict__ p2, const float* __restrict__ p3,
    ushort* __restrict__ hw, ushort* __restrict__ ow1,
    ushort* __restrict__ ow2, ushort* __restrict__ ow3,
    ushort* __restrict__ hid,
    ushort* __restrict__ pT0, ushort* __restrict__ pT1,
    ushort* __restrict__ pT2, ushort* __restrict__ pT3)
{
    int lane = threadIdx.x & 63;
    int r = lane & 15, quad = lane >> 4;
    long wb0 = (long)blockIdx.x * 4 + (threadIdx.x >> 6);
    long nw = (long)gridDim.x * 4;
    for (long wb = wb0; wb < WB_TOTAL; wb += nw) {
        long b = wb;
        float vals[8];
        #pragma unroll
        for (int j = 0; j < 8; ++j) vals[j] = 0.f;
        ushort* dst;
        if (b < WB_HW) {
            long tile = b >> 4, ks = b & 15;
            long v = tile * 16 + r, k = ks * 32 + quad * 8;
            if (v < 20000)      ld8(W0 + v * 512 + k, vals);
            else if (v < VH)    ld8(cw + (v - 20000) * 512 + k, vals);
            dst = hw + b * 512 + (long)lane * 8;
        } else if ((b -= WB_HW) < WB_W1) {
            long tile = b >> 2, ks = b & 3;
            long v = tile * 16 + r, k = ks * 32 + quad * 8;
            if (v < V1) ld8(W1 + v * 128 + k, vals);
            dst = ow1 + b * 512 + (long)lane * 8;
        } else if ((b -= WB_W1) < WB_W2) {
            long v = b * 16 + r;
            if (v < V2) ld8(W2 + v * 32 + quad * 8, vals);
            dst = ow2 + b * 512 + (long)lane * 8;
        } else if ((b -= WB_W2) < WB_W3) {
            long v = b * 16 + r;
            if (v < V3 && quad == 0) ld8(W3 + v * 8, vals);
            dst = ow3 + b * 512 + (long)lane * 8;
        } else if ((b -= WB_W3) < WB_HID) {
            long tile = b >> 4, ks = b & 15;
            long v = tile * 16 + r, k = ks * 32 + quad * 8;
            ld8(hidden + v * 512 + k, vals);
            dst = hid + b * 512 + (long)lane * 8;
        } else if ((b -= WB_HID) < WB_PT0) {
            long tile = b >> 4, ks = b & 15;
            long c = tile * 16 + r, k = ks * 32 + quad * 8;
            #pragma unroll
            for (int j = 0; j < 8; ++j) vals[j] = p0[(k + j) * 512 + c];
            dst = pT0 + b * 512 + (long)lane * 8;
        } else if ((b -= WB_PT0) < WB_PT1) {
            long tile = b >> 4, ks = b & 15;
            long c = tile * 16 + r, k = ks * 32 + quad * 8;
            #pragma unroll
            for (int j = 0; j < 8; ++j) vals[j] = p1[(k + j) * 128 + c];
            dst = pT1 + b * 512 + (long)lane * 8;
        } else if ((b -= WB_PT1) < WB_PT2) {
            long tile = b >> 4, ks = b & 15;
            long c = tile * 16 + r, k = ks * 32 + quad * 8;
            #pragma unroll
            for (int j = 0; j < 8; ++j) vals[j] = p2[(k + j) * 32 + c];
            dst = pT2 + b * 512 + (long)lane * 8;
        } else {
            b -= WB_PT2;
            long tile = b >> 4, ks = b & 15;
            long c = tile * 16 + r, k = ks * 32 + quad * 8;
            if (c < 8) {
                #pragma unroll
                for (int j = 0; j < 8; ++j) vals[j] = p3[(k + j) * 8 + c];
            }
            dst = pT3 + b * 512 + (long)lane * 8;
        }
        u16x8 o;
        #pragma unroll
        for (int j = 0; j < 8; ++j) o[j] = f2bf(vals[j]);
        *(u16x8*)dst = o;
    }
}

// ---------------- prep: padded biases ----------------
#define E_HB  ((long)VH_PAD)
#define E_B1  ((long)V1_PAD)
#define E_B2  ((long)V2_PAD)
#define E_B3  ((long)V3_PAD)
#define E_BIAS (E_HB+E_B1+E_B2+E_B3)

__global__ __launch_bounds__(256) void prep_bias(
    const float* __restrict__ b0, const float* __restrict__ b1,
    const float* __restrict__ b2, const float* __restrict__ b3,
    const float* __restrict__ cb,
    float* __restrict__ hbp, float* __restrict__ ob1,
    float* __restrict__ ob2, float* __restrict__ ob3)
{
    long stride = (long)gridDim.x * blockDim.x;
    for (long i = (long)blockIdx.x * blockDim.x + threadIdx.x; i < E_BIAS; i += stride) {
        long j = i;
        if (j < E_HB) {
            hbp[j] = (j < 20000) ? b0[j] : (j < VH) ? cb[j - 20000] : PAD_BIAS;
        } else if ((j -= E_HB) < E_B1) {
            ob1[j] = (j < V1) ? b1[j] : PAD_BIAS;
        } else if ((j -= E_B1) < E_B2) {
            ob2[j] = (j < V2) ? b2[j] : PAD_BIAS;
        } else { j -= E_B2;
            ob3[j] = (j < V3) ? b3[j] : PAD_BIAS;
        }
    }
}

// ---------------- gemm_h ----------------
__global__ __launch_bounds__(256) void gemm_h(
    const ushort* __restrict__ A, const ushort* __restrict__ Bt,
    ushort* __restrict__ Hout, int dpad)
{
    int wave = threadIdx.x >> 6, lane = threadIdx.x & 63;
    int quad = lane >> 4, colid = lane & 15;
    int m_tile = blockIdx.x * 4 + wave;
    int c_tile = blockIdx.y;
    const ushort* Ab = A + ((long)m_tile * 16) * 512 + lane * 8;
    const ushort* Bb = Bt + ((long)c_tile * 16) * 512 + lane * 8;
    f32x4 acc = {0.f, 0.f, 0.f, 0.f};
    #pragma unroll
    for (int ks = 0; ks < 16; ++ks) {
        s16x8 a = *(const s16x8*)(Ab + ks * 512);
        s16x8 b = *(const s16x8*)(Bb + ks * 512);
        acc = mfma_bf16(a, b, acc);
    }
    int KBo = dpad >> 5;
    int col = c_tile * 16 + colid;
    int ks_o = col >> 5, q_o = (col >> 3) & 3, j_o = col & 7;
    #pragma unroll
    for (int r = 0; r < 4; ++r) {
        int rm = quad * 4 + r;
        Hout[((long)m_tile * KBo + ks_o) * 512 + (q_o * 16 + rm) * 8 + j_o] = f2bf(acc[r]);
    }
}

// ---------------- fused GEMM + exp-sum, LDS-shared W ----------------
// Block = 4 waves = 64 tokens (wave w owns m-tile blockIdx.x*4+w).
// Vocab streamed in groups of 8 tiles (128 rows). W k-slices staged in LDS
// cooperatively (SKS k-steps per stage); all 4 waves consume the same LDS
// fragments -> W pulled through VMEM/L1 once per block, not once per wave.
// Registers: acc[8][4]=32 VGPR + transient b-frag + s_acc -> ~70, no spill
// (r4/r5/r6 post-mortems: register tiles >100 VGPR always spilled).
template<int K, int SKS>
__global__ __launch_bounds__(256) void fused_lse_lds(
    const ushort* __restrict__ A, const ushort* __restrict__ W,
    const float* __restrict__ bias, float* __restrict__ part_s,
    int tpc, int n_chunks)
{
    constexpr int KB = K / 32;
    __shared__ ushort smem[8 * SKS * 512];

    int wave = threadIdx.x >> 6, lane = threadIdx.x & 63;
    int quad = lane >> 4, colid = lane & 15;
    int m_tile = blockIdx.x * 4 + wave;
    int chunk = blockIdx.y;
    int t0 = chunk * tpc;
    const ushort* Ab = A + (long)m_tile * KB * 512 + lane * 8;

    float s_acc[4] = {0.f, 0.f, 0.f, 0.f};

    for (int g = 0; g < tpc; g += 8) {
        f32x4 acc[8];
        #pragma unroll
        for (int u = 0; u < 8; ++u) acc[u] = (f32x4){0.f, 0.f, 0.f, 0.f};

        for (int kb = 0; kb < KB; kb += SKS) {
            __syncthreads();   // protect previous stage's reads
            // stage 8 tiles x SKS k-steps; wave w copies blocks [w*2*SKS, (w+1)*2*SKS)
            #pragma unroll
            for (int c = 0; c < 2 * SKS; ++c) {
                int b = wave * 2 * SKS + c;
                int tile = b / SKS, ksl = b % SKS;
                u16x8 v = *(const u16x8*)(W + ((long)(t0 + g + tile) * KB + kb + ksl) * 512 + lane * 8);
                *(u16x8*)(smem + (long)b * 512 + lane * 8) = v;
            }
            __syncthreads();
            #pragma unroll
            for (int ksl = 0; ksl < SKS; ++ksl) {
                s16x8 a = *(const s16x8*)(Ab + (long)(kb + ksl) * 512);
                #pragma unroll
                for (int u = 0; u < 8; ++u) {
                    s16x8 b = *(const s16x8*)(smem + (long)(u * SKS + ksl) * 512 + lane * 8);
                    acc[u] = mfma_bf16(a, b, acc[u]);
                }
            }
        }
        #pragma unroll
        for (int u = 0; u < 8; ++u) {
            float bval = bias[(t0 + g + u) * 16 + colid];
            #pragma unroll
            for (int r = 0; r < 4; ++r)
                s_acc[r] += __expf(acc[u][r] + bval);
        }
    }
    #pragma unroll
    for (int r = 0; r < 4; ++r) {
        float v = s_acc[r];
        v += __shfl_xor(v, 1);
        v += __shfl_xor(v, 2);
        v += __shfl_xor(v, 4);
        v += __shfl_xor(v, 8);
        if (colid == 0) {
            int m = m_tile * 16 + quad * 4 + r;
            part_s[(long)m * n_chunks + chunk] = v;
        }
    }
}

// ---------------- finalize ----------------
__device__ __forceinline__ float swz_dot(const ushort* __restrict__ H, int m,
                                         const ushort* __restrict__ Wm, long vrow,
                                         int K, int lane)
{
    float d = 0.f;
    if (lane * 8 < K) {
        int ks = lane >> 2, q = lane & 3;
        int KB = K >> 5;
        const ushort* hp = H + ((long)(m >> 4) * KB + ks) * 512 + (q * 16 + (m & 15)) * 8;
        const ushort* wp = Wm + ((vrow >> 4) * KB + ks) * 512 + (q * 16 + (int)(vrow & 15)) * 8;
        #pragma unroll
        for (int j = 0; j < 8; ++j) d += bf2f(hp[j]) * bf2f(wp[j]);
    }
    d += __shfl_xor(d, 1);  d += __shfl_xor(d, 2);  d += __shfl_xor(d, 4);
    d += __shfl_xor(d, 8);  d += __shfl_xor(d, 16); d += __shfl_xor(d, 32);
    return d;
}

__global__ __launch_bounds__(256) void finalize_kernel(
    const int* __restrict__ target,
    const ushort* __restrict__ H0, const ushort* __restrict__ hw,
    const float* __restrict__ hbp, const float* __restrict__ sH,
    const ushort* __restrict__ H1, const ushort* __restrict__ w1,
    const float* __restrict__ b1p, const float* __restrict__ s1,
    const ushort* __restrict__ H2, const ushort* __restrict__ w2,
    const float* __restrict__ b2p, const float* __restrict__ s2,
    const ushort* __restrict__ H3, const ushort* __restrict__ w3,
    const float* __restrict__ b3p, const float* __restrict__ s3,
    float* __restrict__ out)
{
    int wave = threadIdx.x >> 6, lane = threadIdx.x & 63;
    int m = blockIdx.x * 4 + wave;
    int t = target[m];
    int cid = (t >= 20000) + (t >= 40000) + (t >= 200000);

    float s = 0.f;
    for (int i = lane; i < NCH_H; i += 64) s += sH[(long)m * NCH_H + i];
    s += __shfl_xor(s, 1);  s += __shfl_xor(s, 2);  s += __shfl_xor(s, 4);
    s += __shfl_xor(s, 8);  s += __shfl_xor(s, 16); s += __shfl_xor(s, 32);
    float lse_h = __logf(s);

    int hc = (cid == 0) ? t : (20003 - cid);
    float d = swz_dot(H0, m, hw, hc, 512, lane);
    float nll = lse_h - (d + hbp[hc]);

    if (cid > 0) {
        const ushort *Hi, *Wi; const float *bi, *si; int K, nc, l;
        if (cid == 1)      { Hi = H1; Wi = w1; bi = b1p; si = s1; K = 128; nc = NCH_1; l = 20000; }
        else if (cid == 2) { Hi = H2; Wi = w2; bi = b2p; si = s2; K = 32;  nc = NCH_2; l = 40000; }
        else               { Hi = H3; Wi = w3; bi = b3p; si = s3; K = 32;  nc = NCH_3; l = 200000; }
        int rel = t - l;
        float ts = 0.f;
        for (int i = lane; i < nc; i += 64) ts += si[(long)m * nc + i];
        ts += __shfl_xor(ts, 1);  ts += __shfl_xor(ts, 2);  ts += __shfl_xor(ts, 4);
        ts += __shfl_xor(ts, 8);  ts += __shfl_xor(ts, 16); ts += __shfl_xor(ts, 32);
        float lse_t = __logf(ts);
        float dt = swz_dot(Hi, m, Wi, rel, K, lane);
        nll += lse_t - (dt + bi[rel]);
    }
    if (lane == 0) out[m] = nll;
}

// ---------------- host ----------------
extern "C" void kernel_launch(void* const* d_in, const int* in_sizes, int n_in,
                              void* d_out, int out_size, void* d_ws, size_t ws_size,
                              hipStream_t stream) {
    const float* hidden = (const float*)d_in[0];
    const int*   target = (const int*)d_in[1];
    const float* W0 = (const float*)d_in[2];
    const float* b0 = (const float*)d_in[3];
    const float* p0 = (const float*)d_in[4];
    const float* W1 = (const float*)d_in[5];
    const float* b1 = (const float*)d_in[6];
    const float* p1 = (const float*)d_in[7];
    const float* W2 = (const float*)d_in[8];
    const float* b2 = (const float*)d_in[9];
    const float* p2 = (const float*)d_in[10];
    const float* W3 = (const float*)d_in[11];
    const float* b3 = (const float*)d_in[12];
    const float* p3 = (const float*)d_in[13];
    const float* cw = (const float*)d_in[14];
    const float* cb = (const float*)d_in[15];

    char* ws = (char*)d_ws;
    ushort* hw  = (ushort*)(ws + OFF_HW);
    ushort* ow1 = (ushort*)(ws + OFF_W1);
    ushort* ow2 = (ushort*)(ws + OFF_W2);
    ushort* ow3 = (ushort*)(ws + OFF_W3);
    ushort* hid = (ushort*)(ws + OFF_HID);
    ushort* pT0 = (ushort*)(ws + OFF_PT0);
    ushort* pT1 = (ushort*)(ws + OFF_PT1);
    ushort* pT2 = (ushort*)(ws + OFF_PT2);
    ushort* pT3 = (ushort*)(ws + OFF_PT3);
    ushort* H0  = (ushort*)(ws + OFF_H0);
    ushort* H1  = (ushort*)(ws + OFF_H1);
    ushort* H2  = (ushort*)(ws + OFF_H2);
    ushort* H3  = (ushort*)(ws + OFF_H3);
    float* hbp = (float*)(ws + OFF_HB);
    float* b1p = (float*)(ws + OFF_B1);
    float* b2p = (float*)(ws + OFF_B2);
    float* b3p = (float*)(ws + OFF_B3);
    float* sH  = (float*)(ws + OFF_SH);
    float* s1  = (float*)(ws + OFF_S1);
    float* s2  = (float*)(ws + OFF_S2);
    float* s3  = (float*)(ws + OFF_S3);

    prep_wswz<<<10464, 256, 0, stream>>>(hidden, W0, cw, W1, W2, W3,
                                         p0, p1, p2, p3,
                                         hw, ow1, ow2, ow3, hid, pT0, pT1, pT2, pT3);
    prep_bias<<<1072, 256, 0, stream>>>(b0, b1, b2, b3, cb, hbp, b1p, b2p, b3p);

    gemm_h<<<dim3(NTOK / 64, 512 / 16), 256, 0, stream>>>(hid, pT0, H0, 512);
    gemm_h<<<dim3(NTOK / 64, 128 / 16), 256, 0, stream>>>(hid, pT1, H1, 128);
    gemm_h<<<dim3(NTOK / 64, 32 / 16),  256, 0, stream>>>(hid, pT2, H2, 32);
    gemm_h<<<dim3(NTOK / 64, 32 / 16),  256, 0, stream>>>(hid, pT3, H3, 32);

    // 16 x-blocks cover the 1024 tokens (4 waves x 16 tokens each)
    fused_lse_lds<KH, 4><<<dim3(16, NCH_H), 256, 0, stream>>>(H0, hw,  hbp, sH, TPC_H, NCH_H);
    fused_lse_lds<K1, 4><<<dim3(16, NCH_1), 256, 0, stream>>>(H1, ow1, b1p, s1, TPC_1, NCH_1);
    fused_lse_lds<K2, 1><<<dim3(16, NCH_2), 256, 0, stream>>>(H2, ow2, b2p, s2, TPC_2, NCH_2);
    fused_lse_lds<K3, 1><<<dim3(16, NCH_3), 256, 0, stream>>>(H3, ow3, b3p, s3, TPC_3, NCH_3);

    finalize_kernel<<<NTOK / 4, 256, 0, stream>>>(target,
        H0, hw, hbp, sH, H1, ow1, b1p, s1, H2, ow2, b2p, s2, H3, ow3, b3p, s3,
        (float*)d_out);
}

// Round 8
// 282.951 us; speedup vs baseline: 1.2718x; 1.0354x over previous
//
#include <hip/hip_runtime.h>

typedef short s16x8 __attribute__((ext_vector_type(8)));
typedef unsigned short u16x8 __attribute__((ext_vector_type(8)));
typedef float f32x4 __attribute__((ext_vector_type(4)));
typedef float f32x16 __attribute__((ext_vector_type(16)));
typedef unsigned short ushort;

// ---------------- problem constants ----------------
#define NTOK 1024
#define DHID 512

// head: W0 (20000) + cluster_weight (3) = 20003 rows, K=512
#define VH   20003
#define KH   512
#define KB16_H 32
#define NCH_H 80
#define TPC_H 8       // 32-row tiles per chunk: 80*8*32 = 20480
#define VH_PAD 20480

// tail1: 20000 rows, K=128
#define V1   20000
#define K1   128
#define KB16_1 8
#define NCH_1 80
#define TPC_1 8       // 20480
#define V1_PAD 20480

// tail2: 160000 rows, K=32
#define V2   160000
#define K2   32
#define KB16_2 2
#define NCH_2 160
#define TPC_2 32      // 160*32*32 = 163840
#define V2_PAD 163840

// tail3: 67735 rows, real K=8 padded to 16
#define V3   67735
#define K3   16
#define KB16_3 1
#define NCH_3 68
#define TPC_3 32      // 68*32*32 = 69632
#define V3_PAD 69632

#define PAD_BIAS (-1e30f)

// ---------------- ws layout (bytes) ----------------
// W and H matrices live in 32x16 fragment-native layout for mfma_32x32x16:
// block b = tile*KB16 + ks (tile = row/32, ks = k/16), element = lane*8+j with
// row = tile*32 + (lane&31), k = ks*16 + (lane>>5)*8 + j.
// hid / pT* stay in the 16x32 layout for gemm_h's mfma_16x16x32.
#define OFF_HW   0UL
#define OFF_W1   (OFF_HW  + (unsigned long)VH_PAD*KH*2)
#define OFF_W2   (OFF_W1  + (unsigned long)V1_PAD*K1*2)
#define OFF_W3   (OFF_W2  + (unsigned long)V2_PAD*K2*2)
#define OFF_HID  (OFF_W3  + (unsigned long)V3_PAD*K3*2)
#define OFF_PT0  (OFF_HID + (unsigned long)NTOK*DHID*2)
#define OFF_PT1  (OFF_PT0 + (unsigned long)512*DHID*2)
#define OFF_PT2  (OFF_PT1 + (unsigned long)128*DHID*2)
#define OFF_PT3  (OFF_PT2 + (unsigned long)32*DHID*2)
#define OFF_H0   (OFF_PT3 + (unsigned long)16*DHID*2)
#define OFF_H1   (OFF_H0  + (unsigned long)NTOK*512*2)
#define OFF_H2   (OFF_H1  + (unsigned long)NTOK*128*2)
#define OFF_H3   (OFF_H2  + (unsigned long)NTOK*32*2)
#define OFF_HB   (OFF_H3  + (unsigned long)NTOK*16*2)
#define OFF_B1   (OFF_HB  + (unsigned long)VH_PAD*4)
#define OFF_B2   (OFF_B1  + (unsigned long)V1_PAD*4)
#define OFF_B3   (OFF_B2  + (unsigned long)V2_PAD*4)
#define OFF_SH   (OFF_B3  + (unsigned long)V3_PAD*4)
#define OFF_S1   (OFF_SH  + (unsigned long)NTOK*NCH_H*4)
#define OFF_S2   (OFF_S1  + (unsigned long)NTOK*NCH_1*4)
#define OFF_S3   (OFF_S2  + (unsigned long)NTOK*NCH_2*4)

// ---------------- helpers ----------------
__device__ __forceinline__ ushort f2bf(float f) {
    union { float f; unsigned u; } x; x.f = f;
    unsigned r = x.u + 0x7fffu + ((x.u >> 16) & 1u);
    return (ushort)(r >> 16);
}
__device__ __forceinline__ float bf2f(ushort h) {
    union { unsigned u; float f; } x; x.u = ((unsigned)h) << 16;
    return x.f;
}
__device__ __forceinline__ f32x4 mfma_bf16(s16x8 a, s16x8 b, f32x4 c) {
    return __builtin_amdgcn_mfma_f32_16x16x32_bf16(a, b, c, 0, 0, 0);
}
__device__ __forceinline__ f32x16 mfma32_bf16(s16x8 a, s16x8 b, f32x16 c) {
    return __builtin_amdgcn_mfma_f32_32x32x16_bf16(a, b, c, 0, 0, 0);
}
__device__ __forceinline__ void ld8(const float* p, float* v) {
    float4 a = *(const float4*)p, b = *(const float4*)(p + 4);
    v[0]=a.x; v[1]=a.y; v[2]=a.z; v[3]=a.w; v[4]=b.x; v[5]=b.y; v[6]=b.z; v[7]=b.w;
}

// ---------------- prep: wave-per-512-element-block ----------------
#define WB_HW  20480L   // 640 tiles * 32 ks   (32-layout)
#define WB_W1  5120L    // 640 * 8             (32-layout)
#define WB_W2  10240L   // 5120 * 2            (32-layout)
#define WB_W3  2176L    // 2176 * 1            (32-layout, K=16)
#define WB_HID 1024L    // 64 * 16             (16-layout)
#define WB_PT0 512L     // 32 * 16             (16-layout)
#define WB_PT1 128L
#define WB_PT2 32L
#define WB_PT3 16L      // 1 * 16 (dpad=16)
#define WB_TOTAL (WB_HW+WB_W1+WB_W2+WB_W3+WB_HID+WB_PT0+WB_PT1+WB_PT2+WB_PT3) // 39728

__global__ __launch_bounds__(256) void prep_wswz(
    const float* __restrict__ hidden,
    const float* __restrict__ W0, const float* __restrict__ cw,
    const float* __restrict__ W1, const float* __restrict__ W2, const float* __restrict__ W3,
    const float* __restrict__ p0, const float* __restrict__ p1,
    const float* __restrict__ p2, const float* __restrict__ p3,
    ushort* __restrict__ hw, ushort* __restrict__ ow1,
    ushort* __restrict__ ow2, ushort* __restrict__ ow3,
    ushort* __restrict__ hid,
    ushort* __restrict__ pT0, ushort* __restrict__ pT1,
    ushort* __restrict__ pT2, ushort* __restrict__ pT3)
{
    int lane = threadIdx.x & 63;
    int r16 = lane & 15, q16 = lane >> 4;      // 16-layout coords
    int r32 = lane & 31, half = lane >> 5;     // 32-layout coords
    long wb0 = (long)blockIdx.x * 4 + (threadIdx.x >> 6);
    long nw = (long)gridDim.x * 4;
    for (long wb = wb0; wb < WB_TOTAL; wb += nw) {
        long b = wb;
        float vals[8];
        #pragma unroll
        for (int j = 0; j < 8; ++j) vals[j] = 0.f;
        ushort* dst;
        if (b < WB_HW) {                         // head W, K=512, KB16=32
            long tile = b >> 5, ks = b & 31;
            long v = tile * 32 + r32, k = ks * 16 + half * 8;
            if (v < 20000)      ld8(W0 + v * 512 + k, vals);
            else if (v < VH)    ld8(cw + (v - 20000) * 512 + k, vals);
            dst = hw + b * 512 + (long)lane * 8;
        } else if ((b -= WB_HW) < WB_W1) {       // W1, K=128, KB16=8
            long tile = b >> 3, ks = b & 7;
            long v = tile * 32 + r32, k = ks * 16 + half * 8;
            if (v < V1) ld8(W1 + v * 128 + k, vals);
            dst = ow1 + b * 512 + (long)lane * 8;
        } else if ((b -= WB_W1) < WB_W2) {       // W2, K=32, KB16=2
            long tile = b >> 1, ks = b & 1;
            long v = tile * 32 + r32, k = ks * 16 + half * 8;
            if (v < V2) ld8(W2 + v * 32 + k, vals);
            dst = ow2 + b * 512 + (long)lane * 8;
        } else if ((b -= WB_W2) < WB_W3) {       // W3, K=16 (real 8), KB16=1
            long v = b * 32 + r32;
            if (v < V3 && half == 0) ld8(W3 + v * 8, vals);
            dst = ow3 + b * 512 + (long)lane * 8;
        } else if ((b -= WB_W3) < WB_HID) {      // hidden, 16-layout
            long tile = b >> 4, ks = b & 15;
            long v = tile * 16 + r16, k = ks * 32 + q16 * 8;
            ld8(hidden + v * 512 + k, vals);
            dst = hid + b * 512 + (long)lane * 8;
        } else if ((b -= WB_HID) < WB_PT0) {     // projT0 cols of p0 [512][512]
            long tile = b >> 4, ks = b & 15;
            long c = tile * 16 + r16, k = ks * 32 + q16 * 8;
            #pragma unroll
            for (int j = 0; j < 8; ++j) vals[j] = p0[(k + j) * 512 + c];
            dst = pT0 + b * 512 + (long)lane * 8;
        } else if ((b -= WB_PT0) < WB_PT1) {     // projT1 [512][128]
            long tile = b >> 4, ks = b & 15;
            long c = tile * 16 + r16, k = ks * 32 + q16 * 8;
            #pragma unroll
            for (int j = 0; j < 8; ++j) vals[j] = p1[(k + j) * 128 + c];
            dst = pT1 + b * 512 + (long)lane * 8;
        } else if ((b -= WB_PT1) < WB_PT2) {     // projT2 [512][32]
            long tile = b >> 4, ks = b & 15;
            long c = tile * 16 + r16, k = ks * 32 + q16 * 8;
            #pragma unroll
            for (int j = 0; j < 8; ++j) vals[j] = p2[(k + j) * 32 + c];
            dst = pT2 + b * 512 + (long)lane * 8;
        } else {                                 // projT3 [512][8] -> dpad 16
            b -= WB_PT2;
            long ks = b & 15;
            long c = r16, k = ks * 32 + q16 * 8;
            if (c < 8) {
                #pragma unroll
                for (int j = 0; j < 8; ++j) vals[j] = p3[(k + j) * 8 + c];
            }
            dst = pT3 + b * 512 + (long)lane * 8;
        }
        u16x8 o;
        #pragma unroll
        for (int j = 0; j < 8; ++j) o[j] = f2bf(vals[j]);
        *(u16x8*)dst = o;
    }
}

// ---------------- prep: padded biases ----------------
#define E_HB  ((long)VH_PAD)
#define E_B1  ((long)V1_PAD)
#define E_B2  ((long)V2_PAD)
#define E_B3  ((long)V3_PAD)
#define E_BIAS (E_HB+E_B1+E_B2+E_B3)   // 274432 = 1072*256

__global__ __launch_bounds__(256) void prep_bias(
    const float* __restrict__ b0, const float* __restrict__ b1,
    const float* __restrict__ b2, const float* __restrict__ b3,
    const float* __restrict__ cb,
    float* __restrict__ hbp, float* __restrict__ ob1,
    float* __restrict__ ob2, float* __restrict__ ob3)
{
    long stride = (long)gridDim.x * blockDim.x;
    for (long i = (long)blockIdx.x * blockDim.x + threadIdx.x; i < E_BIAS; i += stride) {
        long j = i;
        if (j < E_HB) {
            hbp[j] = (j < 20000) ? b0[j] : (j < VH) ? cb[j - 20000] : PAD_BIAS;
        } else if ((j -= E_HB) < E_B1) {
            ob1[j] = (j < V1) ? b1[j] : PAD_BIAS;
        } else if ((j -= E_B1) < E_B2) {
            ob2[j] = (j < V2) ? b2[j] : PAD_BIAS;
        } else { j -= E_B2;
            ob3[j] = (j < V3) ? b3[j] : PAD_BIAS;
        }
    }
}

// ---------------- gemm_h: H_i = hidden @ proj_i ----------------
// inputs in 16-layout, output H written in 32x16 fragment layout (KB16o = dpad/16)
__global__ __launch_bounds__(256) void gemm_h(
    const ushort* __restrict__ A, const ushort* __restrict__ Bt,
    ushort* __restrict__ Hout, int kb16o)
{
    int wave = threadIdx.x >> 6, lane = threadIdx.x & 63;
    int quad = lane >> 4, colid = lane & 15;
    int m_tile = blockIdx.x * 4 + wave;
    int c_tile = blockIdx.y;
    const ushort* Ab = A + ((long)m_tile * 16) * 512 + lane * 8;
    const ushort* Bb = Bt + ((long)c_tile * 16) * 512 + lane * 8;
    f32x4 acc = {0.f, 0.f, 0.f, 0.f};
    #pragma unroll
    for (int ks = 0; ks < 16; ++ks) {
        s16x8 a = *(const s16x8*)(Ab + ks * 512);
        s16x8 b = *(const s16x8*)(Bb + ks * 512);
        acc = mfma_bf16(a, b, acc);
    }
    #pragma unroll
    for (int r = 0; r < 4; ++r) {
        int m = m_tile * 16 + quad * 4 + r;
        int c = c_tile * 16 + colid;
        long blk = (long)(m >> 5) * kb16o + (c >> 4);
        Hout[blk * 512 + (((c >> 3) & 1) * 32 + (m & 31)) * 8 + (c & 7)] = f2bf(acc[r]);
    }
}

// ---------------- fused GEMM + exp-sum, 32x32x16 MFMA, LDS-shared W ----------------
// Block = 4 waves; wave w owns 32 tokens (m-tile). Vocab streamed in groups of
// 4 32-row tiles (128 rows); W staged in LDS (SKS k-steps per stage), shared by
// all 4 waves. Per k-step per wave: 1 A global load + 4 LDS B reads + 4 MFMAs
// = 1.25 KB LDS per 32.8 kFLOP (2.3x better than the r7 16x16 version).
// acc[4] f32x16 = 64 regs + s_acc[16] -> ~120 total, below the 128 step.
template<int KB16, int SKS>
__global__ __launch_bounds__(256) void fused_lse32(
    const ushort* __restrict__ A, const ushort* __restrict__ W,
    const float* __restrict__ bias, float* __restrict__ part_s,
    int tpc, int n_chunks)
{
    __shared__ ushort smem[4 * SKS * 512];
    int wave = threadIdx.x >> 6, lane = threadIdx.x & 63;
    int col = lane & 31, half = lane >> 5;
    int m_tile = blockIdx.x * 4 + wave;
    int chunk = blockIdx.y;
    int t0 = chunk * tpc;                      // in 32-row tiles
    const ushort* Ab = A + (long)m_tile * KB16 * 512 + lane * 8;

    float s_acc[16];
    #pragma unroll
    for (int r = 0; r < 16; ++r) s_acc[r] = 0.f;

    for (int g = 0; g < tpc; g += 4) {
        f32x16 acc[4];
        #pragma unroll
        for (int u = 0; u < 4; ++u)
            #pragma unroll
            for (int r = 0; r < 16; ++r) acc[u][r] = 0.f;

        for (int kb = 0; kb < KB16; kb += SKS) {
            __syncthreads();   // protect previous stage's reads
            // wave w stages tile w's SKS k-slices (1 KB each)
            #pragma unroll
            for (int c = 0; c < SKS; ++c) {
                u16x8 v = *(const u16x8*)(W + ((long)(t0 + g + wave) * KB16 + kb + c) * 512 + lane * 8);
                *(u16x8*)(smem + (long)(wave * SKS + c) * 512 + lane * 8) = v;
            }
            __syncthreads();
            #pragma unroll
            for (int ksl = 0; ksl < SKS; ++ksl) {
                s16x8 a = *(const s16x8*)(Ab + (long)(kb + ksl) * 512);
                #pragma unroll
                for (int u = 0; u < 4; ++u) {
                    s16x8 b = *(const s16x8*)(smem + (long)(u * SKS + ksl) * 512 + lane * 8);
                    acc[u] = mfma32_bf16(a, b, acc[u]);
                }
            }
        }
        #pragma unroll
        for (int u = 0; u < 4; ++u) {
            float bval = bias[(t0 + g + u) * 32 + col];
            #pragma unroll
            for (int r = 0; r < 16; ++r)
                s_acc[r] += __expf(acc[u][r] + bval);
        }
    }
    // sum over the 32 cols (within each 32-lane half), then lanes col==0 write
    #pragma unroll
    for (int r = 0; r < 16; ++r) {
        float v = s_acc[r];
        v += __shfl_xor(v, 1);
        v += __shfl_xor(v, 2);
        v += __shfl_xor(v, 4);
        v += __shfl_xor(v, 8);
        v += __shfl_xor(v, 16);
        if (col == 0) {
            int row = (r & 3) + 8 * (r >> 2) + 4 * half;
            int m = m_tile * 32 + row;
            part_s[(long)m * n_chunks + chunk] = v;
        }
    }
}

// ---------------- finalize ----------------
// dot over K of H row m with W row vrow, both in 32x16 layout
__device__ __forceinline__ float swz_dot32(const ushort* __restrict__ H, int m,
                                           const ushort* __restrict__ Wm, long vrow,
                                           int K, int KB16, int lane)
{
    float d = 0.f;
    if (lane * 8 < K) {
        const ushort* hp = H + ((long)(m >> 5) * KB16 + (lane >> 1)) * 512
                             + ((lane & 1) * 32 + (m & 31)) * 8;
        const ushort* wp = Wm + ((vrow >> 5) * KB16 + (lane >> 1)) * 512
                              + ((lane & 1) * 32 + (int)(vrow & 31)) * 8;
        #pragma unroll
        for (int j = 0; j < 8; ++j) d += bf2f(hp[j]) * bf2f(wp[j]);
    }
    d += __shfl_xor(d, 1);  d += __shfl_xor(d, 2);  d += __shfl_xor(d, 4);
    d += __shfl_xor(d, 8);  d += __shfl_xor(d, 16); d += __shfl_xor(d, 32);
    return d;
}

__global__ __launch_bounds__(256) void finalize_kernel(
    const int* __restrict__ target,
    const ushort* __restrict__ H0, const ushort* __restrict__ hw,
    const float* __restrict__ hbp, const float* __restrict__ sH,
    const ushort* __restrict__ H1, const ushort* __restrict__ w1,
    const float* __restrict__ b1p, const float* __restrict__ s1,
    const ushort* __restrict__ H2, const ushort* __restrict__ w2,
    const float* __restrict__ b2p, const float* __restrict__ s2,
    const ushort* __restrict__ H3, const ushort* __restrict__ w3,
    const float* __restrict__ b3p, const float* __restrict__ s3,
    float* __restrict__ out)
{
    int wave = threadIdx.x >> 6, lane = threadIdx.x & 63;
    int m = blockIdx.x * 4 + wave;
    int t = target[m];
    int cid = (t >= 20000) + (t >= 40000) + (t >= 200000);

    float s = 0.f;
    for (int i = lane; i < NCH_H; i += 64) s += sH[(long)m * NCH_H + i];
    s += __shfl_xor(s, 1);  s += __shfl_xor(s, 2);  s += __shfl_xor(s, 4);
    s += __shfl_xor(s, 8);  s += __shfl_xor(s, 16); s += __shfl_xor(s, 32);
    float lse_h = __logf(s);

    int hc = (cid == 0) ? t : (20003 - cid);
    float d = swz_dot32(H0, m, hw, hc, 512, KB16_H, lane);
    float nll = lse_h - (d + hbp[hc]);

    if (cid > 0) {
        const ushort *Hi, *Wi; const float *bi, *si; int K, KB16, nc, l;
        if (cid == 1)      { Hi = H1; Wi = w1; bi = b1p; si = s1; K = 128; KB16 = KB16_1; nc = NCH_1; l = 20000; }
        else if (cid == 2) { Hi = H2; Wi = w2; bi = b2p; si = s2; K = 32;  KB16 = KB16_2; nc = NCH_2; l = 40000; }
        else               { Hi = H3; Wi = w3; bi = b3p; si = s3; K = 16;  KB16 = KB16_3; nc = NCH_3; l = 200000; }
        int rel = t - l;
        float ts = 0.f;
        for (int i = lane; i < nc; i += 64) ts += si[(long)m * nc + i];
        ts += __shfl_xor(ts, 1);  ts += __shfl_xor(ts, 2);  ts += __shfl_xor(ts, 4);
        ts += __shfl_xor(ts, 8);  ts += __shfl_xor(ts, 16); ts += __shfl_xor(ts, 32);
        float lse_t = __logf(ts);
        float dt = swz_dot32(Hi, m, Wi, rel, K, KB16, lane);
        nll += lse_t - (dt + bi[rel]);
    }
    if (lane == 0) out[m] = nll;
}

// ---------------- host ----------------
extern "C" void kernel_launch(void* const* d_in, const int* in_sizes, int n_in,
                              void* d_out, int out_size, void* d_ws, size_t ws_size,
                              hipStream_t stream) {
    const float* hidden = (const float*)d_in[0];
    const int*   target = (const int*)d_in[1];
    const float* W0 = (const float*)d_in[2];
    const float* b0 = (const float*)d_in[3];
    const float* p0 = (const float*)d_in[4];
    const float* W1 = (const float*)d_in[5];
    const float* b1 = (const float*)d_in[6];
    const float* p1 = (const float*)d_in[7];
    const float* W2 = (const float*)d_in[8];
    const float* b2 = (const float*)d_in[9];
    const float* p2 = (const float*)d_in[10];
    const float* W3 = (const float*)d_in[11];
    const float* b3 = (const float*)d_in[12];
    const float* p3 = (const float*)d_in[13];
    const float* cw = (const float*)d_in[14];
    const float* cb = (const float*)d_in[15];

    char* ws = (char*)d_ws;
    ushort* hw  = (ushort*)(ws + OFF_HW);
    ushort* ow1 = (ushort*)(ws + OFF_W1);
    ushort* ow2 = (ushort*)(ws + OFF_W2);
    ushort* ow3 = (ushort*)(ws + OFF_W3);
    ushort* hid = (ushort*)(ws + OFF_HID);
    ushort* pT0 = (ushort*)(ws + OFF_PT0);
    ushort* pT1 = (ushort*)(ws + OFF_PT1);
    ushort* pT2 = (ushort*)(ws + OFF_PT2);
    ushort* pT3 = (ushort*)(ws + OFF_PT3);
    ushort* H0  = (ushort*)(ws + OFF_H0);
    ushort* H1  = (ushort*)(ws + OFF_H1);
    ushort* H2  = (ushort*)(ws + OFF_H2);
    ushort* H3  = (ushort*)(ws + OFF_H3);
    float* hbp = (float*)(ws + OFF_HB);
    float* b1p = (float*)(ws + OFF_B1);
    float* b2p = (float*)(ws + OFF_B2);
    float* b3p = (float*)(ws + OFF_B3);
    float* sH  = (float*)(ws + OFF_SH);
    float* s1  = (float*)(ws + OFF_S1);
    float* s2  = (float*)(ws + OFF_S2);
    float* s3  = (float*)(ws + OFF_S3);

    prep_wswz<<<9932, 256, 0, stream>>>(hidden, W0, cw, W1, W2, W3,
                                        p0, p1, p2, p3,
                                        hw, ow1, ow2, ow3, hid, pT0, pT1, pT2, pT3);
    prep_bias<<<1072, 256, 0, stream>>>(b0, b1, b2, b3, cb, hbp, b1p, b2p, b3p);

    gemm_h<<<dim3(NTOK / 64, 512 / 16), 256, 0, stream>>>(hid, pT0, H0, KB16_H);
    gemm_h<<<dim3(NTOK / 64, 128 / 16), 256, 0, stream>>>(hid, pT1, H1, KB16_1);
    gemm_h<<<dim3(NTOK / 64, 32 / 16),  256, 0, stream>>>(hid, pT2, H2, KB16_2);
    gemm_h<<<dim3(NTOK / 64, 16 / 16),  256, 0, stream>>>(hid, pT3, H3, KB16_3);

    // 8 x-blocks cover the 1024 tokens (4 waves x 32 tokens each)
    fused_lse32<KB16_H, 8><<<dim3(8, NCH_H), 256, 0, stream>>>(H0, hw,  hbp, sH, TPC_H, NCH_H);
    fused_lse32<KB16_1, 8><<<dim3(8, NCH_1), 256, 0, stream>>>(H1, ow1, b1p, s1, TPC_1, NCH_1);
    fused_lse32<KB16_2, 2><<<dim3(8, NCH_2), 256, 0, stream>>>(H2, ow2, b2p, s2, TPC_2, NCH_2);
    fused_lse32<KB16_3, 1><<<dim3(8, NCH_3), 256, 0, stream>>>(H3, ow3, b3p, s3, TPC_3, NCH_3);

    finalize_kernel<<<NTOK / 4, 256, 0, stream>>>(target,
        H0, hw, hbp, sH, H1, ow1, b1p, s1, H2, ow2, b2p, s2, H3, ow3, b3p, s3,
        (float*)d_out);
}